// Round 6
// baseline (270.901 us; speedup 1.0000x reference)
//
#include <hip/hip_runtime.h>
#include <stdint.h>

typedef __bf16 bf16;
typedef float f32x4 __attribute__((ext_vector_type(4)));
typedef __bf16 bf16x8 __attribute__((ext_vector_type(8)));
typedef __bf16 bf16x4 __attribute__((ext_vector_type(4)));
typedef __bf16 bf16x2 __attribute__((ext_vector_type(2)));
typedef unsigned u32x2 __attribute__((ext_vector_type(2)));
typedef unsigned u32x4 __attribute__((ext_vector_type(4)));

// async global->LDS, 16B/lane. LDS dest is wave-uniform base + lane*16.
__device__ __forceinline__ void async_load16(const void* g, void* l) {
    __builtin_amdgcn_global_load_lds(
        (const __attribute__((address_space(1))) void*)g,
        (__attribute__((address_space(3))) void*)l, 16, 0, 0);
}

// pack two f32 -> one dword of 2 bf16 (lo first)
__device__ __forceinline__ unsigned pk2(float lo, float hi) {
    bf16x2 t;
    t[0] = (bf16)lo;
    t[1] = (bf16)hi;
    return __builtin_bit_cast(unsigned, t);
}

// in-register 64-lane half/quarter swaps (gfx950). HW-verified correct (v7/v10).
#if __has_builtin(__builtin_amdgcn_permlane32_swap)
#define PLSWAP32(A_, B_) do { u32x2 _r = __builtin_amdgcn_permlane32_swap((A_), (B_), false, false); (A_) = _r[0]; (B_) = _r[1]; } while (0)
#else
#define PLSWAP32(A_, B_) asm("v_permlane32_swap_b32 %0, %1" : "+v"(A_), "+v"(B_))
#endif
#if __has_builtin(__builtin_amdgcn_permlane16_swap)
#define PLSWAP16(A_, B_) do { u32x2 _r = __builtin_amdgcn_permlane16_swap((A_), (B_), false, false); (A_) = _r[0]; (B_) = _r[1]; } while (0)
#else
#define PLSWAP16(A_, B_) asm("v_permlane16_swap_b32 %0, %1" : "+v"(A_), "+v"(B_))
#endif

// ---------------------------------------------------------------------------
// flag[0] = 1 if inputs stored fp32, 0 if bf16. flag[1] = mask-nonzero.
// ---------------------------------------------------------------------------
__global__ void detect_dtype(const unsigned short* __restrict__ q, int* __restrict__ flag) {
    __shared__ int cnt;
    if (threadIdx.x == 0) cnt = 0;
    __syncthreads();
    int c = 0;
    for (int i = threadIdx.x; i < 4096; i += 256) {
        int e = (q[i] >> 7) & 0xFF;
        if (e >= 0xC0) ++c;
    }
    atomicAdd(&cnt, c);
    __syncthreads();
    if (threadIdx.x == 0) { flag[0] = (cnt > 64) ? 1 : 0; flag[1] = 0; }
}

// ---------------------------------------------------------------------------
// Fused prep: grid (64,32,7), 256 threads.
// ---------------------------------------------------------------------------
__global__ void prep(const void* __restrict__ qv, const void* __restrict__ vv,
                     const void* __restrict__ wq, const void* __restrict__ wk,
                     const void* __restrict__ wv, const void* __restrict__ wo,
                     const unsigned int* __restrict__ mask,
                     bf16* __restrict__ Xq, bf16* __restrict__ Xv,
                     bf16* __restrict__ WqT, bf16* __restrict__ WoT,
                     int* __restrict__ flag) {
    __shared__ bf16 t[32][33];
    const int f    = flag[0];
    const int task = blockIdx.z;
    const int bid  = blockIdx.x + 64 * blockIdx.y;  // 0..2047

    if (task < 2) {  // convert 4M elems, 8/thread, 2048 blocks
        const void* x = task ? vv : qv;
        bf16* o = task ? Xv : Xq;
        size_t i = ((size_t)bid * 256 + threadIdx.x) * 8;
        if (f) {
            f32x4 a = ((const f32x4*)x)[i / 4];
            f32x4 b = ((const f32x4*)x)[i / 4 + 1];
            bf16x8 v;
            for (int j = 0; j < 4; ++j) { v[j] = (bf16)a[j]; v[4 + j] = (bf16)b[j]; }
            *(bf16x8*)(o + i) = v;
        } else {
            *(bf16x8*)(o + i) = *(const bf16x8*)((const bf16*)x + i);
        }
    } else if (task < 5) {  // Wq/Wk/Wv transpose: [16][1024][64] -> [16*64][1024]
        if (bid >= 1024) return;
        const void* in = (task == 2) ? wq : ((task == 3) ? wk : wv);
        int sub = bid >> 6, rem = bid & 63;
        int c0 = (rem & 1) * 32, r0 = (rem >> 1) * 32;
        int tx = threadIdx.x & 31, ty = threadIdx.x >> 5;
        size_t base = (size_t)sub * 65536;
        if (f) {
            const float* inF = (const float*)in;
            for (int i = 0; i < 32; i += 8)
                t[ty + i][tx] = (bf16)inF[base + (size_t)(r0 + ty + i) * 64 + (c0 + tx)];
        } else {
            const bf16* inB = (const bf16*)in;
            for (int i = 0; i < 32; i += 8)
                t[ty + i][tx] = inB[base + (size_t)(r0 + ty + i) * 64 + (c0 + tx)];
        }
        __syncthreads();
        bf16* o = WqT + ((size_t)(task - 2) * 16 + sub) * 65536;
        for (int i = 0; i < 32; i += 8)
            o[(size_t)(c0 + ty + i) * 1024 + (r0 + tx)] = t[tx][ty + i];
    } else if (task == 5) {  // Wo transpose [1024][1024]
        if (bid >= 1024) return;
        int c0 = (bid & 31) * 32, r0 = (bid >> 5) * 32;
        int tx = threadIdx.x & 31, ty = threadIdx.x >> 5;
        if (f) {
            const float* inF = (const float*)wo;
            for (int i = 0; i < 32; i += 8)
                t[ty + i][tx] = (bf16)inF[(size_t)(r0 + ty + i) * 1024 + (c0 + tx)];
        } else {
            const bf16* inB = (const bf16*)wo;
            for (int i = 0; i < 32; i += 8)
                t[ty + i][tx] = inB[(size_t)(r0 + ty + i) * 1024 + (c0 + tx)];
        }
        __syncthreads();
        for (int i = 0; i < 32; i += 8)
            WoT[(size_t)(c0 + ty + i) * 1024 + (r0 + tx)] = t[tx][ty + i];
    } else {  // maskscan
        const long nvec = (f ? 4194304L : 2097152L) / 4;
        unsigned int acc = 0;
        long stride = 2048L * 256;
        for (long i = (long)bid * 256 + threadIdx.x; i < nvec; i += stride) {
            uint4 v = ((const uint4*)mask)[i];
            acc |= v.x | v.y | v.z | v.w;
        }
        if (acc) atomicOr(flag + 1, 1);
    }
}

// ---------------------------------------------------------------------------
// Fused QKV GEMM, one launch, grid (8,32,3) = 768 blocks (3/CU).
// ---------------------------------------------------------------------------
__global__ __launch_bounds__(256, 3) void gemm_qkv(
    const bf16* __restrict__ Xq, const void* __restrict__ keyRaw,
    const bf16* __restrict__ Xv, const bf16* __restrict__ Bt,
    const void* __restrict__ b0, const void* __restrict__ b1, const void* __restrict__ b2,
    bf16* __restrict__ Qp, bf16* __restrict__ Kp, bf16* __restrict__ Vt,
    const int* __restrict__ flag) {
    __shared__ __attribute__((aligned(16))) unsigned char AsRaw[128 * 64 * 4];
    __shared__ __attribute__((aligned(16))) bf16 Bs[128 * 64];

    const int f = flag[0];
    const int K = 1024, N = 1024;
    const int z = blockIdx.z;
    const int af = (z == 1) ? f : 0;  // fp32 in-GEMM staging only for key
    const void* Av   = (z == 0) ? (const void*)Xq : ((z == 1) ? keyRaw : (const void*)Xv);
    const void* bias = (z == 0) ? b0 : ((z == 1) ? b1 : b2);
    const bf16* B    = Bt + (size_t)z * 1024 * 1024;

    const int tid  = threadIdx.x;
    const int lane = tid & 63;
    const int w    = tid >> 6;
    const int quad = lane >> 4;
    const int mrow = lane & 15;
    const int m0 = blockIdx.y * 128;
    const int n0 = blockIdx.x * 128;
    const int wm = (w & 1) * 64;
    const int wn = (w >> 1) * 64;

    f32x4 acc[4][4] = {};

    for (int k0 = 0; k0 < K; k0 += 64) {
        if (af) {
            for (int it = 0; it < 8; ++it) {
                int ci  = it * 256 + tid;
                int row = ci >> 4, pc = ci & 15;
                int swz = ((row & 7) << 1) | ((row >> 3) & 1);
                int gc  = pc ^ swz;
                async_load16((const float*)Av + (size_t)(m0 + row) * K + k0 + gc * 4,
                             AsRaw + (size_t)(it * 256 + w * 64) * 16);
            }
        } else {
            for (int it = 0; it < 4; ++it) {
                int ci  = it * 256 + tid;
                int row = ci >> 3, pc = ci & 7;
                int gc  = pc ^ (row & 7);
                async_load16((const bf16*)Av + (size_t)(m0 + row) * K + k0 + gc * 8,
                             (bf16*)AsRaw + (size_t)(it * 256 + w * 64) * 8);
            }
        }
        for (int it = 0; it < 4; ++it) {
            int ci  = it * 256 + tid;
            int row = ci >> 3, pc = ci & 7;
            int gc  = pc ^ (row & 7);
            async_load16(B + (size_t)(n0 + row) * K + k0 + gc * 8,
                         Bs + (size_t)(it * 256 + w * 64) * 8);
        }
        __syncthreads();
        for (int kk = 0; kk < 2; ++kk) {
            bf16x8 afr[4], bfr[4];
            if (af) {
                const float* Asf = (const float*)AsRaw;
                for (int mi = 0; mi < 4; ++mi) {
                    int row = wm + mi * 16 + mrow;
                    int swz = ((row & 7) << 1) | ((row >> 3) & 1);
                    int lc  = (kk * 4 + quad) * 2;
                    f32x4 u0 = *(const f32x4*)(Asf + row * 64 + (lc ^ swz) * 4);
                    f32x4 u1 = *(const f32x4*)(Asf + row * 64 + ((lc + 1) ^ swz) * 4);
                    for (int j = 0; j < 4; ++j) {
                        afr[mi][j]     = (bf16)u0[j];
                        afr[mi][4 + j] = (bf16)u1[j];
                    }
                }
            } else {
                const bf16* Asb = (const bf16*)AsRaw;
                for (int mi = 0; mi < 4; ++mi) {
                    int row = wm + mi * 16 + mrow;
                    int pc  = (kk * 4 + quad) ^ (row & 7);
                    afr[mi] = *(const bf16x8*)(Asb + row * 64 + pc * 8);
                }
            }
            for (int ni = 0; ni < 4; ++ni) {
                int row = wn + ni * 16 + mrow;
                int pc  = (kk * 4 + quad) ^ (row & 7);
                bfr[ni] = *(const bf16x8*)(Bs + row * 64 + pc * 8);
            }
            for (int mi = 0; mi < 4; ++mi)
                for (int ni = 0; ni < 4; ++ni)
                    acc[mi][ni] = __builtin_amdgcn_mfma_f32_16x16x32_bf16(
                        afr[mi], bfr[ni], acc[mi][ni], 0, 0, 0);
        }
        __syncthreads();
    }

    const float scl = (z == 0) ? 0.18033688f : 1.0f;  // 0.125 * log2(e) into Q
    for (int ni = 0; ni < 4; ++ni) {
        int n    = n0 + wn + ni * 16 + mrow;
        float bv = f ? ((const float*)bias)[n] : (float)((const bf16*)bias)[n];
        for (int mi = 0; mi < 4; ++mi) {
            int mb = m0 + wm + mi * 16 + quad * 4;
            if (z == 2) {
                bf16x4 pk;
                for (int r = 0; r < 4; ++r) pk[r] = (bf16)(acc[mi][ni][r] + bv);
                *(bf16x4*)(Vt + (((size_t)(mb >> 11) * 1024 + n) << 11) + (mb & 2047)) = pk;
            } else {
                bf16* P = (z == 0) ? Qp : Kp;
                for (int r = 0; r < 4; ++r)
                    P[(size_t)(mb + r) * N + n] = (bf16)((acc[mi][ni][r] + bv) * scl);
            }
        }
    }
}

// ---------------------------------------------------------------------------
// Output projection GEMM: 128x64 tile -> 512 blocks (2/CU).
// ---------------------------------------------------------------------------
__global__ __launch_bounds__(256, 2) void gemm_out(
    const bf16* __restrict__ A, const bf16* __restrict__ Bt,
    const void* __restrict__ bias, void* __restrict__ Cout,
    const int* __restrict__ flag) {
    __shared__ __attribute__((aligned(16))) bf16 As[128 * 64];
    __shared__ __attribute__((aligned(16))) bf16 Bs[64 * 64];

    const int f = flag[0];
    const int K = 1024, N = 1024;
    const int tid  = threadIdx.x;
    const int lane = tid & 63;
    const int w    = tid >> 6;
    const int quad = lane >> 4;
    const int mrow = lane & 15;
    const int m0 = blockIdx.y * 128;
    const int n0 = blockIdx.x * 64;
    const int wm = (w & 1) * 64;
    const int wn = (w >> 1) * 32;

    f32x4 acc[4][2] = {};

    for (int k0 = 0; k0 < K; k0 += 64) {
        for (int it = 0; it < 4; ++it) {
            int ci  = it * 256 + tid;
            int row = ci >> 3, pc = ci & 7;
            int gc  = pc ^ (row & 7);
            async_load16(A + (size_t)(m0 + row) * K + k0 + gc * 8,
                         As + (size_t)(it * 256 + w * 64) * 8);
        }
        for (int it = 0; it < 2; ++it) {
            int ci  = it * 256 + tid;
            int row = ci >> 3, pc = ci & 7;
            int gc  = pc ^ (row & 7);
            async_load16(Bt + (size_t)(n0 + row) * K + k0 + gc * 8,
                         Bs + (size_t)(it * 256 + w * 64) * 8);
        }
        __syncthreads();
        for (int kk = 0; kk < 2; ++kk) {
            bf16x8 afr[4], bfr[2];
            for (int mi = 0; mi < 4; ++mi) {
                int row = wm + mi * 16 + mrow;
                int pc  = (kk * 4 + quad) ^ (row & 7);
                afr[mi] = *(const bf16x8*)(As + row * 64 + pc * 8);
            }
            for (int ni = 0; ni < 2; ++ni) {
                int row = wn + ni * 16 + mrow;
                int pc  = (kk * 4 + quad) ^ (row & 7);
                bfr[ni] = *(const bf16x8*)(Bs + row * 64 + pc * 8);
            }
            for (int mi = 0; mi < 4; ++mi)
                for (int ni = 0; ni < 2; ++ni)
                    acc[mi][ni] = __builtin_amdgcn_mfma_f32_16x16x32_bf16(
                        afr[mi], bfr[ni], acc[mi][ni], 0, 0, 0);
        }
        __syncthreads();
    }

    for (int ni = 0; ni < 2; ++ni) {
        int n    = n0 + wn + ni * 16 + mrow;
        float bv = f ? ((const float*)bias)[n] : (float)((const bf16*)bias)[n];
        for (int mi = 0; mi < 4; ++mi) {
            int mb = m0 + wm + mi * 16 + quad * 4;
            for (int r = 0; r < 4; ++r) {
                float val = acc[mi][ni][r] + bv;
                if (f) ((float*)Cout)[(size_t)(mb + r) * N + n] = val;
                else   ((bf16*)Cout)[(size_t)(mb + r) * N + n] = (bf16)val;
            }
        }
    }
}

// ---------------------------------------------------------------------------
// Flash attention v11 = v10 (512 thr, 8 waves, reg-P permlane, XCD remap) +
// counted-vmcnt 3-buffer pipeline (T3/T4): __syncthreads (which drains
// vmcnt(0)) replaced by per-wave `s_waitcnt vmcnt(2)` + raw s_barrier.
// Staged loads get 2 FCOMPs of flight time and never block the barrier.
//
// Invariant: each thread issues exactly 2 loads per STAGE. Prologue stages
// tiles 0,1 (4 outstanding). Loop t: vmcnt(2) retires the oldest 2 =
// buffer (t%3)'s loads (vmcnt is in-order); s_barrier -> visible to all;
// STAGE buffer (t+2)%3 (WAR-safe: its last reader FCOMP(t-1) completed on
// all waves before this barrier); FCOMP(t%3). Tail wraps the tile index
// ((t+2)&31 -> re-stages tiles 0,1 into dead buffers) so vmcnt counting
// stays uniform. vmcnt(0) once after the loop. sched_barrier(0) after the
// barrier pins ordering (guide rule #18).
// LDS 48KB (3x(K 8KB + V 8KB)) -> still 2 blocks/CU, 4 waves/SIMD.
// ---------------------------------------------------------------------------
__global__ __launch_bounds__(512, 4) void flash_attn(
    const bf16* __restrict__ Qp, const bf16* __restrict__ Kp,
    const bf16* __restrict__ Vt, const void* __restrict__ maskv,
    bf16* __restrict__ O, const int* __restrict__ flag) {
    __shared__ __attribute__((aligned(16))) bf16 Ks[3][4096];
    __shared__ __attribute__((aligned(16))) bf16 Vs[3][4096];

    const int f       = flag[0];
    const int useMask = flag[1];
    const int tid  = threadIdx.x;          // 0..511
    const int lane = tid & 63;
    const int w    = tid >> 6;             // 0..7
    const int quad = lane >> 4;
    const int c    = lane & 15;

    // XCD-aware remap: all 16 s0-blocks of one (b,h) land on one XCD.
    const int flat = blockIdx.x + 16 * (blockIdx.y + 16 * blockIdx.z);
    const int rx   = flat & 7;
    const int sx   = flat >> 3;
    const int pair = rx + 8 * (sx >> 4);
    const int s0   = (sx & 15) * 128;
    const int h    = pair & 15;
    const int b    = pair >> 4;

    const size_t qkBase = (size_t)b * 2048 * 1024 + h * 64;
    const size_t vtBase = ((size_t)b * 1024 + h * 64) * 2048;

    // staging: exactly one 16B K-chunk + one 16B V-chunk per thread
    const int r0 = tid >> 3, g0 = (tid & 7) ^ (r0 & 7);
    const bf16* kp0 = Kp + qkBase + (size_t)r0 * 1024 + g0 * 8;
    const bf16* vp0 = Vt + vtBase + (size_t)r0 * 2048 + g0 * 8;

#define STAGE(B_, T_) do {                                                      \
        async_load16(kp0 + (size_t)(T_) * 1024, &Ks[B_][(size_t)(w * 64) * 8]); \
        async_load16(vp0 + (T_),                &Vs[B_][(size_t)(w * 64) * 8]); \
    } while (0)

    // invariant per-lane LDS frag base pointers (q-independent)
    const bf16* kf0 = &Ks[0][c * 64 + ((0 + quad) ^ (c & 7)) * 8];
    const bf16* kf1 = &Ks[0][c * 64 + ((4 + quad) ^ (c & 7)) * 8];
    const bf16* vf0 = &Vs[0][c * 64 + ((0 + quad) ^ (c & 7)) * 8];
    const bf16* vf1 = &Vs[0][c * 64 + ((4 + quad) ^ (c & 7)) * 8];

    // Q fragment in registers: this wave's 16 rows as the MFMA B-operand
    const bf16* qrow = Qp + qkBase + (size_t)(s0 + w * 16 + c) * 1024;
    bf16x8 aq0 = *(const bf16x8*)(qrow + quad * 8);
    bf16x8 aq1 = *(const bf16x8*)(qrow + 32 + quad * 8);

    f32x4 o_acc[4] = {};   // [ni]: rows q = w*16+quad*4+r, col dv = ni*16+c
    float l_s = 0.f;

    const size_t mb0 = (size_t)(s0 + w * 16 + c) * 2048;

// OFF_ = runtime LDS element offset (cur*4096) selecting the buffer
#define FCOMP(OFF_, T_) do {                                                             \
        f32x4 sc[4] = {};                                                                \
        _Pragma("unroll") for (int tt = 0; tt < 4; ++tt) {                               \
            bf16x8 ak0 = *(const bf16x8*)(kf0 + (OFF_) + tt * 1024);                     \
            bf16x8 ak1 = *(const bf16x8*)(kf1 + (OFF_) + tt * 1024);                     \
            sc[tt] = __builtin_amdgcn_mfma_f32_16x16x32_bf16(ak0, aq0, sc[tt], 0, 0, 0); \
            sc[tt] = __builtin_amdgcn_mfma_f32_16x16x32_bf16(ak1, aq1, sc[tt], 0, 0, 0); \
        }                                                                                \
        if (useMask) {                                                                   \
            const size_t mr = mb0 + (T_);                                                \
            _Pragma("unroll") for (int tt = 0; tt < 4; ++tt) {                           \
                if (f) {                                                                 \
                    f32x4 mk = *(const f32x4*)((const float*)maskv + mr + tt * 16 + quad * 4); \
                    for (int r = 0; r < 4; ++r) sc[tt][r] += mk[r] * 1.44269504f;        \
                } else {                                                                 \
                    bf16x4 mk = *(const bf16x4*)((const bf16*)maskv + mr + tt * 16 + quad * 4); \
                    for (int r = 0; r < 4; ++r) sc[tt][r] += (float)mk[r] * 1.44269504f; \
                }                                                                        \
            }                                                                            \
        }                                                                                \
        unsigned Wp[4][2];                                                               \
        {                                                                                \
            float rsum = 0.f;                                                            \
            _Pragma("unroll") for (int tt = 0; tt < 4; ++tt) {                           \
                float p0 = exp2f(sc[tt][0]), p1 = exp2f(sc[tt][1]);                      \
                float p2 = exp2f(sc[tt][2]), p3 = exp2f(sc[tt][3]);                      \
                rsum += (p0 + p1) + (p2 + p3);                                           \
                Wp[tt][0] = pk2(p0, p1);                                                 \
                Wp[tt][1] = pk2(p2, p3);                                                 \
            }                                                                            \
            l_s += rsum;                                                                 \
        }                                                                                \
        _Pragma("unroll") for (int kk = 0; kk < 2; ++kk) {                               \
            unsigned a0 = Wp[2 * kk][0], b0v = Wp[2 * kk + 1][0];                        \
            unsigned a1 = Wp[2 * kk][1], b1v = Wp[2 * kk + 1][1];                        \
            PLSWAP32(a0, b0v);                                                           \
            PLSWAP16(a0, b0v);                                                           \
            PLSWAP32(a1, b1v);                                                           \
            PLSWAP16(a1, b1v);                                                           \
            u32x4 uv; uv[0] = a0; uv[1] = a1; uv[2] = b0v; uv[3] = b1v;                  \
            bf16x8 ap = __builtin_bit_cast(bf16x8, uv);                                  \
            const bf16* vfb = (kk ? vf1 : vf0) + (OFF_);                                 \
            _Pragma("unroll") for (int ni = 0; ni < 4; ++ni) {                           \
                bf16x8 bv = *(const bf16x8*)(vfb + ni * 1024);                           \
                o_acc[ni] = __builtin_amdgcn_mfma_f32_16x16x32_bf16(ap, bv, o_acc[ni], 0, 0, 0); \
            }                                                                            \
        }                                                                                \
    } while (0)

    // counted-vmcnt 3-buffer pipeline (see header comment)
    STAGE(0, 0);
    STAGE(1, 64);
    int cur = 0;
    for (int t = 0; t < 32; ++t) {
        asm volatile("s_waitcnt vmcnt(2)" ::: "memory");
        __builtin_amdgcn_s_barrier();
        __builtin_amdgcn_sched_barrier(0);
        int nxt = cur + 2;
        if (nxt >= 3) nxt -= 3;
        STAGE(nxt, ((t + 2) & 31) * 64);   // tail wraps: dead-buffer restage keeps counts uniform
        FCOMP(cur * 4096, t * 64);
        ++cur;
        if (cur == 3) cur = 0;
    }
    asm volatile("s_waitcnt vmcnt(0)" ::: "memory");
#undef STAGE
#undef FCOMP

    // epilogue: reduce l across quads, gather per-row l, store O
    {
        float ls = l_s;
        ls += __shfl_xor(ls, 16, 64);
        ls += __shfl_xor(ls, 32, 64);
        for (int r = 0; r < 4; ++r) {
            float lv   = __shfl(ls, quad * 4 + r, 64);
            float inv  = 1.0f / lv;
            size_t roff = (size_t)(b * 2048 + s0 + w * 16 + quad * 4 + r) * 1024 + h * 64;
            for (int ni = 0; ni < 4; ++ni)
                O[roff + ni * 16 + c] = (bf16)(o_acc[ni][r] * inv);
        }
    }
}

// ---------------------------------------------------------------------------
extern "C" void kernel_launch(void* const* d_in, const int* in_sizes, int n_in,
                              void* d_out, int out_size, void* d_ws, size_t ws_size,
                              hipStream_t stream) {
    bf16* ws = (bf16*)d_ws;
    (void)in_sizes; (void)n_in; (void)out_size; (void)ws_size;

    const size_t MM = 1024 * 1024;
    int*  flag = (int*)ws;           // flag[0]=fp32?, flag[1]=mask-nonzero
    bf16* WqT  = ws + 8;             // 3 MM
    bf16* WoT  = WqT + 3 * MM;       // 1 MM
    bf16* Qp   = WoT + MM;           // 4 MM (pre-scaled by 0.125*log2e)
    bf16* Kp   = Qp + 4 * MM;        // 4 MM
    bf16* Xq   = Kp + 4 * MM;        // 4 MM (query bf16; becomes AO after flash)
    bf16* AO   = Xq;                 //        -> ws total 16 MM + 8 (proven fit)
    bf16* Xv   = (bf16*)d_out;            // d_out lower 8 MB: value bf16
    bf16* Vt   = (bf16*)d_out + 4 * MM;   // d_out upper 8 MB: V^T (dead after flash)

    detect_dtype<<<1, 256, 0, stream>>>((const unsigned short*)d_in[0], flag);

    prep<<<dim3(64, 32, 7), 256, 0, stream>>>(d_in[0], d_in[2], d_in[4], d_in[6],
                                              d_in[8], d_in[10],
                                              (const unsigned int*)d_in[3],
                                              Xq, Xv, WqT, WoT, flag);

    gemm_qkv<<<dim3(8, 32, 3), 256, 0, stream>>>(Xq, d_in[1], Xv, WqT,
                                                 d_in[5], d_in[7], d_in[9],
                                                 Qp, Kp, Vt, flag);

    flash_attn<<<dim3(16, 16, 2), 512, 0, stream>>>(Qp, Kp, Vt, d_in[3], AO, flag);

    gemm_out<<<dim3(16, 32, 1), 256, 0, stream>>>(AO, WoT, d_in[11], d_out, flag);
}

// Round 7
// 267.858 us; speedup vs baseline: 1.0114x; 1.0114x over previous
//
#include <hip/hip_runtime.h>
#include <stdint.h>

typedef __bf16 bf16;
typedef float f32x4 __attribute__((ext_vector_type(4)));
typedef __bf16 bf16x8 __attribute__((ext_vector_type(8)));
typedef __bf16 bf16x4 __attribute__((ext_vector_type(4)));
typedef __bf16 bf16x2 __attribute__((ext_vector_type(2)));
typedef unsigned u32x2 __attribute__((ext_vector_type(2)));
typedef unsigned u32x4 __attribute__((ext_vector_type(4)));

// async global->LDS, 16B/lane. LDS dest is wave-uniform base + lane*16.
__device__ __forceinline__ void async_load16(const void* g, void* l) {
    __builtin_amdgcn_global_load_lds(
        (const __attribute__((address_space(1))) void*)g,
        (__attribute__((address_space(3))) void*)l, 16, 0, 0);
}

// pack two f32 -> one dword of 2 bf16 (lo first)
__device__ __forceinline__ unsigned pk2(float lo, float hi) {
    bf16x2 t;
    t[0] = (bf16)lo;
    t[1] = (bf16)hi;
    return __builtin_bit_cast(unsigned, t);
}

// in-register 64-lane half/quarter swaps (gfx950). HW-verified correct (v7/v10).
#if __has_builtin(__builtin_amdgcn_permlane32_swap)
#define PLSWAP32(A_, B_) do { u32x2 _r = __builtin_amdgcn_permlane32_swap((A_), (B_), false, false); (A_) = _r[0]; (B_) = _r[1]; } while (0)
#else
#define PLSWAP32(A_, B_) asm("v_permlane32_swap_b32 %0, %1" : "+v"(A_), "+v"(B_))
#endif
#if __has_builtin(__builtin_amdgcn_permlane16_swap)
#define PLSWAP16(A_, B_) do { u32x2 _r = __builtin_amdgcn_permlane16_swap((A_), (B_), false, false); (A_) = _r[0]; (B_) = _r[1]; } while (0)
#else
#define PLSWAP16(A_, B_) asm("v_permlane16_swap_b32 %0, %1" : "+v"(A_), "+v"(B_))
#endif

// ---------------------------------------------------------------------------
// flag[0] = 1 if inputs stored fp32, 0 if bf16. flag[1] = mask-nonzero.
// ---------------------------------------------------------------------------
__global__ void detect_dtype(const unsigned short* __restrict__ q, int* __restrict__ flag) {
    __shared__ int cnt;
    if (threadIdx.x == 0) cnt = 0;
    __syncthreads();
    int c = 0;
    for (int i = threadIdx.x; i < 4096; i += 256) {
        int e = (q[i] >> 7) & 0xFF;
        if (e >= 0xC0) ++c;
    }
    atomicAdd(&cnt, c);
    __syncthreads();
    if (threadIdx.x == 0) { flag[0] = (cnt > 64) ? 1 : 0; flag[1] = 0; }
}

// ---------------------------------------------------------------------------
// Fused prep: grid (64,32,7 or 8), 256 threads.
//  task 0: convert query -> Xq      task 1: convert value -> Xv
//  task 2/3/4: transpose Wq/Wk/Wv -> WqT[z][n][k]
//  task 5: transpose Wo -> WoT      task 6: maskscan -> flag[1]
//  task 7 (only when useXk): convert key -> Xk (fp32 inputs only)
// ---------------------------------------------------------------------------
__global__ void prep(const void* __restrict__ qv, const void* __restrict__ vv,
                     const void* __restrict__ kvraw,
                     const void* __restrict__ wq, const void* __restrict__ wk,
                     const void* __restrict__ wv, const void* __restrict__ wo,
                     const unsigned int* __restrict__ mask,
                     bf16* __restrict__ Xq, bf16* __restrict__ Xv,
                     bf16* __restrict__ Xk,
                     bf16* __restrict__ WqT, bf16* __restrict__ WoT,
                     int* __restrict__ flag) {
    __shared__ bf16 t[32][33];
    const int f    = flag[0];
    const int task = blockIdx.z;
    const int bid  = blockIdx.x + 64 * blockIdx.y;  // 0..2047

    if (task < 2) {  // convert 4M elems, 8/thread, 2048 blocks
        const void* x = task ? vv : qv;
        bf16* o = task ? Xv : Xq;
        size_t i = ((size_t)bid * 256 + threadIdx.x) * 8;
        if (f) {
            f32x4 a = ((const f32x4*)x)[i / 4];
            f32x4 b = ((const f32x4*)x)[i / 4 + 1];
            bf16x8 v;
            for (int j = 0; j < 4; ++j) { v[j] = (bf16)a[j]; v[4 + j] = (bf16)b[j]; }
            *(bf16x8*)(o + i) = v;
        } else {
            *(bf16x8*)(o + i) = *(const bf16x8*)((const bf16*)x + i);
        }
    } else if (task < 5) {  // Wq/Wk/Wv transpose: [16][1024][64] -> [16*64][1024]
        if (bid >= 1024) return;
        const void* in = (task == 2) ? wq : ((task == 3) ? wk : wv);
        int sub = bid >> 6, rem = bid & 63;
        int c0 = (rem & 1) * 32, r0 = (rem >> 1) * 32;
        int tx = threadIdx.x & 31, ty = threadIdx.x >> 5;
        size_t base = (size_t)sub * 65536;
        if (f) {
            const float* inF = (const float*)in;
            for (int i = 0; i < 32; i += 8)
                t[ty + i][tx] = (bf16)inF[base + (size_t)(r0 + ty + i) * 64 + (c0 + tx)];
        } else {
            const bf16* inB = (const bf16*)in;
            for (int i = 0; i < 32; i += 8)
                t[ty + i][tx] = inB[base + (size_t)(r0 + ty + i) * 64 + (c0 + tx)];
        }
        __syncthreads();
        bf16* o = WqT + ((size_t)(task - 2) * 16 + sub) * 65536;
        for (int i = 0; i < 32; i += 8)
            o[(size_t)(c0 + ty + i) * 1024 + (r0 + tx)] = t[tx][ty + i];
    } else if (task == 5) {  // Wo transpose [1024][1024]
        if (bid >= 1024) return;
        int c0 = (bid & 31) * 32, r0 = (bid >> 5) * 32;
        int tx = threadIdx.x & 31, ty = threadIdx.x >> 5;
        if (f) {
            const float* inF = (const float*)wo;
            for (int i = 0; i < 32; i += 8)
                t[ty + i][tx] = (bf16)inF[(size_t)(r0 + ty + i) * 1024 + (c0 + tx)];
        } else {
            const bf16* inB = (const bf16*)wo;
            for (int i = 0; i < 32; i += 8)
                t[ty + i][tx] = inB[(size_t)(r0 + ty + i) * 1024 + (c0 + tx)];
        }
        __syncthreads();
        for (int i = 0; i < 32; i += 8)
            WoT[(size_t)(c0 + ty + i) * 1024 + (r0 + tx)] = t[tx][ty + i];
    } else if (task == 6) {  // maskscan
        const long nvec = (f ? 4194304L : 2097152L) / 4;
        unsigned int acc = 0;
        long stride = 2048L * 256;
        for (long i = (long)bid * 256 + threadIdx.x; i < nvec; i += stride) {
            uint4 v = ((const uint4*)mask)[i];
            acc |= v.x | v.y | v.z | v.w;
        }
        if (acc) atomicOr(flag + 1, 1);
    } else {  // task 7: key convert (only reached when useXk; skip if bf16 input)
        if (!f) return;
        size_t i = ((size_t)bid * 256 + threadIdx.x) * 8;
        f32x4 a = ((const f32x4*)kvraw)[i / 4];
        f32x4 b2 = ((const f32x4*)kvraw)[i / 4 + 1];
        bf16x8 v;
        for (int j = 0; j < 4; ++j) { v[j] = (bf16)a[j]; v[4 + j] = (bf16)b2[j]; }
        *(bf16x8*)(Xk + i) = v;
    }
}

// ---------------------------------------------------------------------------
// Fused QKV GEMM, one launch, grid (8,32,3) = 768 blocks (3/CU).
// z=0: A=Xq (bf16) -> Qp (*0.125*log2e); z=1: A=key (Xk bf16 when useXk&f,
// else raw with in-GEMM fp32 convert) -> Kp; z=2: A=Xv -> Vt (transposed).
// ---------------------------------------------------------------------------
__global__ __launch_bounds__(256, 3) void gemm_qkv(
    const bf16* __restrict__ Xq, const void* __restrict__ keyRaw,
    const bf16* __restrict__ Xv, const bf16* __restrict__ Xk,
    const bf16* __restrict__ Bt,
    const void* __restrict__ b0, const void* __restrict__ b1, const void* __restrict__ b2,
    bf16* __restrict__ Qp, bf16* __restrict__ Kp, bf16* __restrict__ Vt,
    const int* __restrict__ flag, const int useXk) {
    __shared__ __attribute__((aligned(16))) unsigned char AsRaw[128 * 64 * 4];
    __shared__ __attribute__((aligned(16))) bf16 Bs[128 * 64];

    const int f = flag[0];
    const int K = 1024, N = 1024;
    const int z = blockIdx.z;
    const int af = (z == 1 && !useXk) ? f : 0;  // fp32 in-GEMM staging fallback
    const void* Av = (z == 0) ? (const void*)Xq
                   : (z == 1) ? ((f && useXk) ? (const void*)Xk : keyRaw)
                              : (const void*)Xv;
    const void* bias = (z == 0) ? b0 : ((z == 1) ? b1 : b2);
    const bf16* B    = Bt + (size_t)z * 1024 * 1024;

    const int tid  = threadIdx.x;
    const int lane = tid & 63;
    const int w    = tid >> 6;
    const int quad = lane >> 4;
    const int mrow = lane & 15;
    const int m0 = blockIdx.y * 128;
    const int n0 = blockIdx.x * 128;
    const int wm = (w & 1) * 64;
    const int wn = (w >> 1) * 64;

    f32x4 acc[4][4] = {};

    for (int k0 = 0; k0 < K; k0 += 64) {
        if (af) {
            for (int it = 0; it < 8; ++it) {
                int ci  = it * 256 + tid;
                int row = ci >> 4, pc = ci & 15;
                int swz = ((row & 7) << 1) | ((row >> 3) & 1);
                int gc  = pc ^ swz;
                async_load16((const float*)Av + (size_t)(m0 + row) * K + k0 + gc * 4,
                             AsRaw + (size_t)(it * 256 + w * 64) * 16);
            }
        } else {
            for (int it = 0; it < 4; ++it) {
                int ci  = it * 256 + tid;
                int row = ci >> 3, pc = ci & 7;
                int gc  = pc ^ (row & 7);
                async_load16((const bf16*)Av + (size_t)(m0 + row) * K + k0 + gc * 8,
                             (bf16*)AsRaw + (size_t)(it * 256 + w * 64) * 8);
            }
        }
        for (int it = 0; it < 4; ++it) {
            int ci  = it * 256 + tid;
            int row = ci >> 3, pc = ci & 7;
            int gc  = pc ^ (row & 7);
            async_load16(B + (size_t)(n0 + row) * K + k0 + gc * 8,
                         Bs + (size_t)(it * 256 + w * 64) * 8);
        }
        __syncthreads();
        for (int kk = 0; kk < 2; ++kk) {
            bf16x8 afr[4], bfr[4];
            if (af) {
                const float* Asf = (const float*)AsRaw;
                for (int mi = 0; mi < 4; ++mi) {
                    int row = wm + mi * 16 + mrow;
                    int swz = ((row & 7) << 1) | ((row >> 3) & 1);
                    int lc  = (kk * 4 + quad) * 2;
                    f32x4 u0 = *(const f32x4*)(Asf + row * 64 + (lc ^ swz) * 4);
                    f32x4 u1 = *(const f32x4*)(Asf + row * 64 + ((lc + 1) ^ swz) * 4);
                    for (int j = 0; j < 4; ++j) {
                        afr[mi][j]     = (bf16)u0[j];
                        afr[mi][4 + j] = (bf16)u1[j];
                    }
                }
            } else {
                const bf16* Asb = (const bf16*)AsRaw;
                for (int mi = 0; mi < 4; ++mi) {
                    int row = wm + mi * 16 + mrow;
                    int pc  = (kk * 4 + quad) ^ (row & 7);
                    afr[mi] = *(const bf16x8*)(Asb + row * 64 + pc * 8);
                }
            }
            for (int ni = 0; ni < 4; ++ni) {
                int row = wn + ni * 16 + mrow;
                int pc  = (kk * 4 + quad) ^ (row & 7);
                bfr[ni] = *(const bf16x8*)(Bs + row * 64 + pc * 8);
            }
            for (int mi = 0; mi < 4; ++mi)
                for (int ni = 0; ni < 4; ++ni)
                    acc[mi][ni] = __builtin_amdgcn_mfma_f32_16x16x32_bf16(
                        afr[mi], bfr[ni], acc[mi][ni], 0, 0, 0);
        }
        __syncthreads();
    }

    const float scl = (z == 0) ? 0.18033688f : 1.0f;  // 0.125 * log2(e) into Q
    for (int ni = 0; ni < 4; ++ni) {
        int n    = n0 + wn + ni * 16 + mrow;
        float bv = f ? ((const float*)bias)[n] : (float)((const bf16*)bias)[n];
        for (int mi = 0; mi < 4; ++mi) {
            int mb = m0 + wm + mi * 16 + quad * 4;
            if (z == 2) {
                bf16x4 pk;
                for (int r = 0; r < 4; ++r) pk[r] = (bf16)(acc[mi][ni][r] + bv);
                *(bf16x4*)(Vt + (((size_t)(mb >> 11) * 1024 + n) << 11) + (mb & 2047)) = pk;
            } else {
                bf16* P = (z == 0) ? Qp : Kp;
                for (int r = 0; r < 4; ++r)
                    P[(size_t)(mb + r) * N + n] = (bf16)((acc[mi][ni][r] + bv) * scl);
            }
        }
    }
}

// ---------------------------------------------------------------------------
// Output projection GEMM: 128x64 tile -> 512 blocks (2/CU).
// ---------------------------------------------------------------------------
__global__ __launch_bounds__(256, 2) void gemm_out(
    const bf16* __restrict__ A, const bf16* __restrict__ Bt,
    const void* __restrict__ bias, void* __restrict__ Cout,
    const int* __restrict__ flag) {
    __shared__ __attribute__((aligned(16))) bf16 As[128 * 64];
    __shared__ __attribute__((aligned(16))) bf16 Bs[64 * 64];

    const int f = flag[0];
    const int K = 1024, N = 1024;
    const int tid  = threadIdx.x;
    const int lane = tid & 63;
    const int w    = tid >> 6;
    const int quad = lane >> 4;
    const int mrow = lane & 15;
    const int m0 = blockIdx.y * 128;
    const int n0 = blockIdx.x * 64;
    const int wm = (w & 1) * 64;
    const int wn = (w >> 1) * 32;

    f32x4 acc[4][2] = {};

    for (int k0 = 0; k0 < K; k0 += 64) {
        for (int it = 0; it < 4; ++it) {
            int ci  = it * 256 + tid;
            int row = ci >> 3, pc = ci & 7;
            int gc  = pc ^ (row & 7);
            async_load16(A + (size_t)(m0 + row) * K + k0 + gc * 8,
                         As + (size_t)(it * 256 + w * 64) * 8);
        }
        for (int it = 0; it < 2; ++it) {
            int ci  = it * 256 + tid;
            int row = ci >> 3, pc = ci & 7;
            int gc  = pc ^ (row & 7);
            async_load16(Bt + (size_t)(n0 + row) * K + k0 + gc * 8,
                         Bs + (size_t)(it * 256 + w * 64) * 8);
        }
        __syncthreads();
        for (int kk = 0; kk < 2; ++kk) {
            bf16x8 afr[4], bfr[2];
            for (int mi = 0; mi < 4; ++mi) {
                int row = wm + mi * 16 + mrow;
                int pc  = (kk * 4 + quad) ^ (row & 7);
                afr[mi] = *(const bf16x8*)(As + row * 64 + pc * 8);
            }
            for (int ni = 0; ni < 2; ++ni) {
                int row = wn + ni * 16 + mrow;
                int pc  = (kk * 4 + quad) ^ (row & 7);
                bfr[ni] = *(const bf16x8*)(Bs + row * 64 + pc * 8);
            }
            for (int mi = 0; mi < 4; ++mi)
                for (int ni = 0; ni < 2; ++ni)
                    acc[mi][ni] = __builtin_amdgcn_mfma_f32_16x16x32_bf16(
                        afr[mi], bfr[ni], acc[mi][ni], 0, 0, 0);
        }
        __syncthreads();
    }

    for (int ni = 0; ni < 2; ++ni) {
        int n    = n0 + wn + ni * 16 + mrow;
        float bv = f ? ((const float*)bias)[n] : (float)((const bf16*)bias)[n];
        for (int mi = 0; mi < 4; ++mi) {
            int mb = m0 + wm + mi * 16 + quad * 4;
            for (int r = 0; r < 4; ++r) {
                float val = acc[mi][ni][r] + bv;
                if (f) ((float*)Cout)[(size_t)(mb + r) * N + n] = val;
                else   ((bf16*)Cout)[(size_t)(mb + r) * N + n] = (bf16)val;
            }
        }
    }
}

// ---------------------------------------------------------------------------
// Flash attention v12 = v10 (512 thr, 8 waves, reg-P permlane, XCD remap,
// proven 65.4us) + MFMA row-sum: l[q] accumulated by one extra
// mfma(ap, ones, o_l) per kk (B=all-ones -> every output column = row sum).
// Removes 16 v_add_f32 per FCOMP (VALU-bound per counters: VALUBusy 60 vs
// MfmaUtil 21) and the entire epilogue shuffle reduce; the 2 extra MFMAs
// land on the 79%-idle MFMA pipe. l now sums the same bf16-rounded P as the
// PV numerator (consistent rounding).
// v11 post-mortem: counted-vmcnt 3-buffer regressed (65.4->75.0) -> reverted
// to the 2-buffer __syncthreads skeleton.
// ---------------------------------------------------------------------------
__global__ __launch_bounds__(512, 4) void flash_attn(
    const bf16* __restrict__ Qp, const bf16* __restrict__ Kp,
    const bf16* __restrict__ Vt, const void* __restrict__ maskv,
    bf16* __restrict__ O, const int* __restrict__ flag) {
    __shared__ __attribute__((aligned(16))) bf16 Ks[2][4096];
    __shared__ __attribute__((aligned(16))) bf16 Vs[2][4096];

    const int f       = flag[0];
    const int useMask = flag[1];
    const int tid  = threadIdx.x;          // 0..511
    const int lane = tid & 63;
    const int w    = tid >> 6;             // 0..7
    const int quad = lane >> 4;
    const int c    = lane & 15;

    // XCD-aware remap: all 16 s0-blocks of one (b,h) land on one XCD.
    const int flat = blockIdx.x + 16 * (blockIdx.y + 16 * blockIdx.z);
    const int rx   = flat & 7;
    const int sx   = flat >> 3;
    const int pair = rx + 8 * (sx >> 4);
    const int s0   = (sx & 15) * 128;
    const int h    = pair & 15;
    const int b    = pair >> 4;

    const size_t qkBase = (size_t)b * 2048 * 1024 + h * 64;
    const size_t vtBase = ((size_t)b * 1024 + h * 64) * 2048;

    // staging: exactly one 16B K-chunk + one 16B V-chunk per thread
    const int r0 = tid >> 3, g0 = (tid & 7) ^ (r0 & 7);
    const bf16* kp0 = Kp + qkBase + (size_t)r0 * 1024 + g0 * 8;
    const bf16* vp0 = Vt + vtBase + (size_t)r0 * 2048 + g0 * 8;

#define STAGE(B_, T_) do {                                                      \
        async_load16(kp0 + (size_t)(T_) * 1024, &Ks[B_][(size_t)(w * 64) * 8]); \
        async_load16(vp0 + (T_),                &Vs[B_][(size_t)(w * 64) * 8]); \
    } while (0)

    // invariant per-lane LDS frag base pointers (q-independent)
    const bf16* kf0 = &Ks[0][c * 64 + ((0 + quad) ^ (c & 7)) * 8];
    const bf16* kf1 = &Ks[0][c * 64 + ((4 + quad) ^ (c & 7)) * 8];
    const bf16* vf0 = &Vs[0][c * 64 + ((0 + quad) ^ (c & 7)) * 8];
    const bf16* vf1 = &Vs[0][c * 64 + ((4 + quad) ^ (c & 7)) * 8];

    // Q fragment in registers: this wave's 16 rows as the MFMA B-operand
    const bf16* qrow = Qp + qkBase + (size_t)(s0 + w * 16 + c) * 1024;
    bf16x8 aq0 = *(const bf16x8*)(qrow + quad * 8);
    bf16x8 aq1 = *(const bf16x8*)(qrow + 32 + quad * 8);

    // all-ones bf16x8 B-operand for the row-sum MFMA
    u32x4 ou; ou[0] = 0x3F803F80u; ou[1] = 0x3F803F80u; ou[2] = 0x3F803F80u; ou[3] = 0x3F803F80u;
    const bf16x8 vones = __builtin_bit_cast(bf16x8, ou);

    f32x4 o_acc[4] = {};   // [ni]: rows q = w*16+quad*4+r, col dv = ni*16+c
    f32x4 o_l = {};        // row-sum accumulator: o_l[r] = l[q] (all c identical)

    const size_t mb0 = (size_t)(s0 + w * 16 + c) * 2048;

#define FCOMP(IB_, T_) do {                                                              \
        f32x4 sc[4] = {};                                                                \
        _Pragma("unroll") for (int tt = 0; tt < 4; ++tt) {                               \
            bf16x8 ak0 = *(const bf16x8*)(kf0 + (IB_) * 4096 + tt * 1024);               \
            bf16x8 ak1 = *(const bf16x8*)(kf1 + (IB_) * 4096 + tt * 1024);               \
            sc[tt] = __builtin_amdgcn_mfma_f32_16x16x32_bf16(ak0, aq0, sc[tt], 0, 0, 0); \
            sc[tt] = __builtin_amdgcn_mfma_f32_16x16x32_bf16(ak1, aq1, sc[tt], 0, 0, 0); \
        }                                                                                \
        if (useMask) {                                                                   \
            const size_t mr = mb0 + (T_);                                                \
            _Pragma("unroll") for (int tt = 0; tt < 4; ++tt) {                           \
                if (f) {                                                                 \
                    f32x4 mk = *(const f32x4*)((const float*)maskv + mr + tt * 16 + quad * 4); \
                    for (int r = 0; r < 4; ++r) sc[tt][r] += mk[r] * 1.44269504f;        \
                } else {                                                                 \
                    bf16x4 mk = *(const bf16x4*)((const bf16*)maskv + mr + tt * 16 + quad * 4); \
                    for (int r = 0; r < 4; ++r) sc[tt][r] += (float)mk[r] * 1.44269504f; \
                }                                                                        \
            }                                                                            \
        }                                                                                \
        unsigned Wp[4][2];                                                               \
        _Pragma("unroll") for (int tt = 0; tt < 4; ++tt) {                               \
            Wp[tt][0] = pk2(exp2f(sc[tt][0]), exp2f(sc[tt][1]));                         \
            Wp[tt][1] = pk2(exp2f(sc[tt][2]), exp2f(sc[tt][3]));                         \
        }                                                                                \
        _Pragma("unroll") for (int kk = 0; kk < 2; ++kk) {                               \
            unsigned a0 = Wp[2 * kk][0], b0v = Wp[2 * kk + 1][0];                        \
            unsigned a1 = Wp[2 * kk][1], b1v = Wp[2 * kk + 1][1];                        \
            PLSWAP32(a0, b0v);                                                           \
            PLSWAP16(a0, b0v);                                                           \
            PLSWAP32(a1, b1v);                                                           \
            PLSWAP16(a1, b1v);                                                           \
            u32x4 uv; uv[0] = a0; uv[1] = a1; uv[2] = b0v; uv[3] = b1v;                  \
            bf16x8 ap = __builtin_bit_cast(bf16x8, uv);                                  \
            const bf16* vfb = kk ? vf1 : vf0;                                            \
            _Pragma("unroll") for (int ni = 0; ni < 4; ++ni) {                           \
                bf16x8 bv = *(const bf16x8*)(vfb + (IB_) * 4096 + ni * 1024);            \
                o_acc[ni] = __builtin_amdgcn_mfma_f32_16x16x32_bf16(ap, bv, o_acc[ni], 0, 0, 0); \
            }                                                                            \
            o_l = __builtin_amdgcn_mfma_f32_16x16x32_bf16(ap, vones, o_l, 0, 0, 0);      \
        }                                                                                \
    } while (0)

    STAGE(0, 0);
    for (int t0 = 0; t0 < 2048; t0 += 128) {
        __syncthreads();                       // buf0 staging visible
        STAGE(1, t0 + 64);
        FCOMP(0, t0);
        __syncthreads();                       // buf1 staging visible
        if (t0 + 128 < 2048) STAGE(0, t0 + 128);
        FCOMP(1, t0 + 64);
    }
#undef STAGE
#undef FCOMP

    // epilogue: l[q] sits in o_l[r] (replicated across c) -> no cross-lane ops
    for (int r = 0; r < 4; ++r) {
        float inv = 1.0f / o_l[r];
        size_t roff = (size_t)(b * 2048 + s0 + w * 16 + quad * 4 + r) * 1024 + h * 64;
        for (int ni = 0; ni < 4; ++ni)
            O[roff + ni * 16 + c] = (bf16)(o_acc[ni][r] * inv);
    }
}

// ---------------------------------------------------------------------------
extern "C" void kernel_launch(void* const* d_in, const int* in_sizes, int n_in,
                              void* d_out, int out_size, void* d_ws, size_t ws_size,
                              hipStream_t stream) {
    bf16* ws = (bf16*)d_ws;
    (void)in_sizes; (void)n_in; (void)out_size;

    const size_t MM = 1024 * 1024;
    int*  flag = (int*)ws;           // flag[0]=fp32?, flag[1]=mask-nonzero
    bf16* WqT  = ws + 8;             // 3 MM
    bf16* WoT  = WqT + 3 * MM;       // 1 MM
    bf16* Qp   = WoT + MM;           // 4 MM (pre-scaled by 0.125*log2e)
    bf16* Kp   = Qp + 4 * MM;        // 4 MM
    bf16* Xq   = Kp + 4 * MM;        // 4 MM (query bf16; becomes AO after flash)
    bf16* AO   = Xq;                 //        -> 16 MM + 8 (proven fit)
    bf16* Xk   = Xq + 4 * MM;        // 4 MM key bf16 (only if ws_size allows)
    bf16* Xv   = (bf16*)d_out;            // d_out lower 8 MB: value bf16
    bf16* Vt   = (bf16*)d_out + 4 * MM;   // d_out upper 8 MB: V^T (dead after flash)

    // Host guard: Xk needs ws up to 20 MM bf16 + 16 B of flags.
    const int useXk = (ws_size >= (size_t)(20 * MM) * sizeof(bf16) + 16) ? 1 : 0;

    detect_dtype<<<1, 256, 0, stream>>>((const unsigned short*)d_in[0], flag);

    prep<<<dim3(64, 32, useXk ? 8 : 7), 256, 0, stream>>>(
        d_in[0], d_in[2], d_in[1], d_in[4], d_in[6], d_in[8], d_in[10],
        (const unsigned int*)d_in[3], Xq, Xv, Xk, WqT, WoT, flag);

    gemm_qkv<<<dim3(8, 32, 3), 256, 0, stream>>>(Xq, d_in[1], Xv, Xk, WqT,
                                                 d_in[5], d_in[7], d_in[9],
                                                 Qp, Kp, Vt, flag, useXk);

    flash_attn<<<dim3(16, 16, 2), 512, 0, stream>>>(Qp, Kp, Vt, d_in[3], AO, flag);

    gemm_out<<<dim3(16, 32, 1), 256, 0, stream>>>(AO, WoT, d_in[11], d_out, flag);
}

// Round 8
// 253.186 us; speedup vs baseline: 1.0700x; 1.0580x over previous
//
#include <hip/hip_runtime.h>
#include <stdint.h>

typedef __bf16 bf16;
typedef float f32x4 __attribute__((ext_vector_type(4)));
typedef __bf16 bf16x8 __attribute__((ext_vector_type(8)));
typedef __bf16 bf16x4 __attribute__((ext_vector_type(4)));
typedef __bf16 bf16x2 __attribute__((ext_vector_type(2)));
typedef unsigned u32x2 __attribute__((ext_vector_type(2)));
typedef unsigned u32x4 __attribute__((ext_vector_type(4)));

// async global->LDS, 16B/lane. LDS dest is wave-uniform base + lane*16.
__device__ __forceinline__ void async_load16(const void* g, void* l) {
    __builtin_amdgcn_global_load_lds(
        (const __attribute__((address_space(1))) void*)g,
        (__attribute__((address_space(3))) void*)l, 16, 0, 0);
}

// pack two f32 -> one dword of 2 bf16 (lo first)
__device__ __forceinline__ unsigned pk2(float lo, float hi) {
    bf16x2 t;
    t[0] = (bf16)lo;
    t[1] = (bf16)hi;
    return __builtin_bit_cast(unsigned, t);
}

// in-register 64-lane half/quarter swaps (gfx950). HW-verified correct (v7/v10).
#if __has_builtin(__builtin_amdgcn_permlane32_swap)
#define PLSWAP32(A_, B_) do { u32x2 _r = __builtin_amdgcn_permlane32_swap((A_), (B_), false, false); (A_) = _r[0]; (B_) = _r[1]; } while (0)
#else
#define PLSWAP32(A_, B_) asm("v_permlane32_swap_b32 %0, %1" : "+v"(A_), "+v"(B_))
#endif
#if __has_builtin(__builtin_amdgcn_permlane16_swap)
#define PLSWAP16(A_, B_) do { u32x2 _r = __builtin_amdgcn_permlane16_swap((A_), (B_), false, false); (A_) = _r[0]; (B_) = _r[1]; } while (0)
#else
#define PLSWAP16(A_, B_) asm("v_permlane16_swap_b32 %0, %1" : "+v"(A_), "+v"(B_))
#endif

// ---------------------------------------------------------------------------
// flag[0] = 1 if inputs stored fp32, 0 if bf16. flag[1] = mask-nonzero.
// ---------------------------------------------------------------------------
__global__ void detect_dtype(const unsigned short* __restrict__ q, int* __restrict__ flag) {
    __shared__ int cnt;
    if (threadIdx.x == 0) cnt = 0;
    __syncthreads();
    int c = 0;
    for (int i = threadIdx.x; i < 4096; i += 256) {
        int e = (q[i] >> 7) & 0xFF;
        if (e >= 0xC0) ++c;
    }
    atomicAdd(&cnt, c);
    __syncthreads();
    if (threadIdx.x == 0) { flag[0] = (cnt > 64) ? 1 : 0; flag[1] = 0; }
}

// ---------------------------------------------------------------------------
// Fused prep: grid (64,32,7 or 8), 256 threads.
//  task 0: convert query -> Xq      task 1: convert value -> Xv
//  task 2/3/4: transpose Wq/Wk/Wv -> WqT[z][n][k]
//  task 5: transpose Wo -> WoT      task 6: maskscan -> flag[1]
//  task 7 (only when useXk): convert key -> Xk (fp32 inputs only)
// ---------------------------------------------------------------------------
__global__ void prep(const void* __restrict__ qv, const void* __restrict__ vv,
                     const void* __restrict__ kvraw,
                     const void* __restrict__ wq, const void* __restrict__ wk,
                     const void* __restrict__ wv, const void* __restrict__ wo,
                     const unsigned int* __restrict__ mask,
                     bf16* __restrict__ Xq, bf16* __restrict__ Xv,
                     bf16* __restrict__ Xk,
                     bf16* __restrict__ WqT, bf16* __restrict__ WoT,
                     int* __restrict__ flag) {
    __shared__ bf16 t[32][33];
    const int f    = flag[0];
    const int task = blockIdx.z;
    const int bid  = blockIdx.x + 64 * blockIdx.y;  // 0..2047

    if (task < 2) {  // convert 4M elems, 8/thread, 2048 blocks
        const void* x = task ? vv : qv;
        bf16* o = task ? Xv : Xq;
        size_t i = ((size_t)bid * 256 + threadIdx.x) * 8;
        if (f) {
            f32x4 a = ((const f32x4*)x)[i / 4];
            f32x4 b = ((const f32x4*)x)[i / 4 + 1];
            bf16x8 v;
            for (int j = 0; j < 4; ++j) { v[j] = (bf16)a[j]; v[4 + j] = (bf16)b[j]; }
            *(bf16x8*)(o + i) = v;
        } else {
            *(bf16x8*)(o + i) = *(const bf16x8*)((const bf16*)x + i);
        }
    } else if (task < 5) {  // Wq/Wk/Wv transpose: [16][1024][64] -> [16*64][1024]
        if (bid >= 1024) return;
        const void* in = (task == 2) ? wq : ((task == 3) ? wk : wv);
        int sub = bid >> 6, rem = bid & 63;
        int c0 = (rem & 1) * 32, r0 = (rem >> 1) * 32;
        int tx = threadIdx.x & 31, ty = threadIdx.x >> 5;
        size_t base = (size_t)sub * 65536;
        if (f) {
            const float* inF = (const float*)in;
            for (int i = 0; i < 32; i += 8)
                t[ty + i][tx] = (bf16)inF[base + (size_t)(r0 + ty + i) * 64 + (c0 + tx)];
        } else {
            const bf16* inB = (const bf16*)in;
            for (int i = 0; i < 32; i += 8)
                t[ty + i][tx] = inB[base + (size_t)(r0 + ty + i) * 64 + (c0 + tx)];
        }
        __syncthreads();
        bf16* o = WqT + ((size_t)(task - 2) * 16 + sub) * 65536;
        for (int i = 0; i < 32; i += 8)
            o[(size_t)(c0 + ty + i) * 1024 + (r0 + tx)] = t[tx][ty + i];
    } else if (task == 5) {  // Wo transpose [1024][1024]
        if (bid >= 1024) return;
        int c0 = (bid & 31) * 32, r0 = (bid >> 5) * 32;
        int tx = threadIdx.x & 31, ty = threadIdx.x >> 5;
        if (f) {
            const float* inF = (const float*)wo;
            for (int i = 0; i < 32; i += 8)
                t[ty + i][tx] = (bf16)inF[(size_t)(r0 + ty + i) * 1024 + (c0 + tx)];
        } else {
            const bf16* inB = (const bf16*)wo;
            for (int i = 0; i < 32; i += 8)
                t[ty + i][tx] = inB[(size_t)(r0 + ty + i) * 1024 + (c0 + tx)];
        }
        __syncthreads();
        for (int i = 0; i < 32; i += 8)
            WoT[(size_t)(c0 + ty + i) * 1024 + (r0 + tx)] = t[tx][ty + i];
    } else if (task == 6) {  // maskscan
        const long nvec = (f ? 4194304L : 2097152L) / 4;
        unsigned int acc = 0;
        long stride = 2048L * 256;
        for (long i = (long)bid * 256 + threadIdx.x; i < nvec; i += stride) {
            uint4 v = ((const uint4*)mask)[i];
            acc |= v.x | v.y | v.z | v.w;
        }
        if (acc) atomicOr(flag + 1, 1);
    } else {  // task 7: key convert (only reached when useXk; skip if bf16 input)
        if (!f) return;
        size_t i = ((size_t)bid * 256 + threadIdx.x) * 8;
        f32x4 a = ((const f32x4*)kvraw)[i / 4];
        f32x4 b2 = ((const f32x4*)kvraw)[i / 4 + 1];
        bf16x8 v;
        for (int j = 0; j < 4; ++j) { v[j] = (bf16)a[j]; v[4 + j] = (bf16)b2[j]; }
        *(bf16x8*)(Xk + i) = v;
    }
}

// ---------------------------------------------------------------------------
// Fused QKV GEMM, grid (8,32,3) = 768 blocks (3/CU), XCD-aware remap:
// the 8 n-blocks sharing one 256KB A-panel run on ONE XCD (A-panel fetched
// once per XCD instead of 8x across XCDs). Bijection: flat=bx+8by+256bz;
// r=flat&7, s=flat>>3; x=s&7, j=s>>3, y=r+8*(j&3), z=j>>2  (8*8*4*3=768).
// z=0: A=Xq -> Qp (*0.125*log2e); z=1: A=key (Xk bf16 when useXk&f, else
// raw fp32 in-GEMM convert) -> Kp; z=2: A=Xv -> Vt (transposed store).
// ---------------------------------------------------------------------------
__global__ __launch_bounds__(256, 3) void gemm_qkv(
    const bf16* __restrict__ Xq, const void* __restrict__ keyRaw,
    const bf16* __restrict__ Xv, const bf16* __restrict__ Xk,
    const bf16* __restrict__ Bt,
    const void* __restrict__ b0, const void* __restrict__ b1, const void* __restrict__ b2,
    bf16* __restrict__ Qp, bf16* __restrict__ Kp, bf16* __restrict__ Vt,
    const int* __restrict__ flag, const int useXk) {
    __shared__ __attribute__((aligned(16))) unsigned char AsRaw[128 * 64 * 4];
    __shared__ __attribute__((aligned(16))) bf16 Bs[128 * 64];

    const int f = flag[0];
    const int K = 1024, N = 1024;

    // XCD-aware remap (see header)
    const int flat = blockIdx.x + 8 * blockIdx.y + 256 * blockIdx.z;
    const int rxw  = flat & 7;
    const int sxw  = flat >> 3;        // 0..95
    const int xb   = sxw & 7;
    const int jb   = sxw >> 3;         // 0..11
    const int yb   = rxw + 8 * (jb & 3);
    const int z    = jb >> 2;

    const int af = (z == 1 && !useXk) ? f : 0;  // fp32 in-GEMM staging fallback
    const void* Av = (z == 0) ? (const void*)Xq
                   : (z == 1) ? ((f && useXk) ? (const void*)Xk : keyRaw)
                              : (const void*)Xv;
    const void* bias = (z == 0) ? b0 : ((z == 1) ? b1 : b2);
    const bf16* B    = Bt + (size_t)z * 1024 * 1024;

    const int tid  = threadIdx.x;
    const int lane = tid & 63;
    const int w    = tid >> 6;
    const int quad = lane >> 4;
    const int mrow = lane & 15;
    const int m0 = yb * 128;
    const int n0 = xb * 128;
    const int wm = (w & 1) * 64;
    const int wn = (w >> 1) * 64;

    f32x4 acc[4][4] = {};

    for (int k0 = 0; k0 < K; k0 += 64) {
        if (af) {
            for (int it = 0; it < 8; ++it) {
                int ci  = it * 256 + tid;
                int row = ci >> 4, pc = ci & 15;
                int swz = ((row & 7) << 1) | ((row >> 3) & 1);
                int gc  = pc ^ swz;
                async_load16((const float*)Av + (size_t)(m0 + row) * K + k0 + gc * 4,
                             AsRaw + (size_t)(it * 256 + w * 64) * 16);
            }
        } else {
            for (int it = 0; it < 4; ++it) {
                int ci  = it * 256 + tid;
                int row = ci >> 3, pc = ci & 7;
                int gc  = pc ^ (row & 7);
                async_load16((const bf16*)Av + (size_t)(m0 + row) * K + k0 + gc * 8,
                             (bf16*)AsRaw + (size_t)(it * 256 + w * 64) * 8);
            }
        }
        for (int it = 0; it < 4; ++it) {
            int ci  = it * 256 + tid;
            int row = ci >> 3, pc = ci & 7;
            int gc  = pc ^ (row & 7);
            async_load16(B + (size_t)(n0 + row) * K + k0 + gc * 8,
                         Bs + (size_t)(it * 256 + w * 64) * 8);
        }
        __syncthreads();
        for (int kk = 0; kk < 2; ++kk) {
            bf16x8 afr[4], bfr[4];
            if (af) {
                const float* Asf = (const float*)AsRaw;
                for (int mi = 0; mi < 4; ++mi) {
                    int row = wm + mi * 16 + mrow;
                    int swz = ((row & 7) << 1) | ((row >> 3) & 1);
                    int lc  = (kk * 4 + quad) * 2;
                    f32x4 u0 = *(const f32x4*)(Asf + row * 64 + (lc ^ swz) * 4);
                    f32x4 u1 = *(const f32x4*)(Asf + row * 64 + ((lc + 1) ^ swz) * 4);
                    for (int j = 0; j < 4; ++j) {
                        afr[mi][j]     = (bf16)u0[j];
                        afr[mi][4 + j] = (bf16)u1[j];
                    }
                }
            } else {
                const bf16* Asb = (const bf16*)AsRaw;
                for (int mi = 0; mi < 4; ++mi) {
                    int row = wm + mi * 16 + mrow;
                    int pc  = (kk * 4 + quad) ^ (row & 7);
                    afr[mi] = *(const bf16x8*)(Asb + row * 64 + pc * 8);
                }
            }
            for (int ni = 0; ni < 4; ++ni) {
                int row = wn + ni * 16 + mrow;
                int pc  = (kk * 4 + quad) ^ (row & 7);
                bfr[ni] = *(const bf16x8*)(Bs + row * 64 + pc * 8);
            }
            for (int mi = 0; mi < 4; ++mi)
                for (int ni = 0; ni < 4; ++ni)
                    acc[mi][ni] = __builtin_amdgcn_mfma_f32_16x16x32_bf16(
                        afr[mi], bfr[ni], acc[mi][ni], 0, 0, 0);
        }
        __syncthreads();
    }

    const float scl = (z == 0) ? 0.18033688f : 1.0f;  // 0.125 * log2(e) into Q
    for (int ni = 0; ni < 4; ++ni) {
        int n    = n0 + wn + ni * 16 + mrow;
        float bv = f ? ((const float*)bias)[n] : (float)((const bf16*)bias)[n];
        for (int mi = 0; mi < 4; ++mi) {
            int mb = m0 + wm + mi * 16 + quad * 4;
            if (z == 2) {
                bf16x4 pk;
                for (int r = 0; r < 4; ++r) pk[r] = (bf16)(acc[mi][ni][r] + bv);
                *(bf16x4*)(Vt + (((size_t)(mb >> 11) * 1024 + n) << 11) + (mb & 2047)) = pk;
            } else {
                bf16* P = (z == 0) ? Qp : Kp;
                for (int r = 0; r < 4; ++r)
                    P[(size_t)(mb + r) * N + n] = (bf16)((acc[mi][ni][r] + bv) * scl);
            }
        }
    }
}

// ---------------------------------------------------------------------------
// Output projection GEMM: 128x64 tile, grid (16,32) = 512 blocks (2/CU),
// XCD-aware remap: the 16 n-blocks sharing one A-panel run on one XCD.
// Bijection: flat=bx+16by; r=flat&7, s=flat>>3; x=s&15, y=r+8*(s>>4).
// Per-XCD working set: 4 A-panels (1MB) + WoT (2MB) < 4MB L2.
// ---------------------------------------------------------------------------
__global__ __launch_bounds__(256, 2) void gemm_out(
    const bf16* __restrict__ A, const bf16* __restrict__ Bt,
    const void* __restrict__ bias, void* __restrict__ Cout,
    const int* __restrict__ flag) {
    __shared__ __attribute__((aligned(16))) bf16 As[128 * 64];
    __shared__ __attribute__((aligned(16))) bf16 Bs[64 * 64];

    const int f = flag[0];
    const int K = 1024, N = 1024;
    const int tid  = threadIdx.x;
    const int lane = tid & 63;
    const int w    = tid >> 6;
    const int quad = lane >> 4;
    const int mrow = lane & 15;

    // XCD-aware remap (see header)
    const int flat = blockIdx.x + 16 * blockIdx.y;
    const int rxw  = flat & 7;
    const int sxw  = flat >> 3;        // 0..63
    const int xb   = sxw & 15;
    const int yb   = rxw + 8 * (sxw >> 4);

    const int m0 = yb * 128;
    const int n0 = xb * 64;
    const int wm = (w & 1) * 64;
    const int wn = (w >> 1) * 32;

    f32x4 acc[4][2] = {};

    for (int k0 = 0; k0 < K; k0 += 64) {
        for (int it = 0; it < 4; ++it) {
            int ci  = it * 256 + tid;
            int row = ci >> 3, pc = ci & 7;
            int gc  = pc ^ (row & 7);
            async_load16(A + (size_t)(m0 + row) * K + k0 + gc * 8,
                         As + (size_t)(it * 256 + w * 64) * 8);
        }
        for (int it = 0; it < 2; ++it) {
            int ci  = it * 256 + tid;
            int row = ci >> 3, pc = ci & 7;
            int gc  = pc ^ (row & 7);
            async_load16(Bt + (size_t)(n0 + row) * K + k0 + gc * 8,
                         Bs + (size_t)(it * 256 + w * 64) * 8);
        }
        __syncthreads();
        for (int kk = 0; kk < 2; ++kk) {
            bf16x8 afr[4], bfr[2];
            for (int mi = 0; mi < 4; ++mi) {
                int row = wm + mi * 16 + mrow;
                int pc  = (kk * 4 + quad) ^ (row & 7);
                afr[mi] = *(const bf16x8*)(As + row * 64 + pc * 8);
            }
            for (int ni = 0; ni < 2; ++ni) {
                int row = wn + ni * 16 + mrow;
                int pc  = (kk * 4 + quad) ^ (row & 7);
                bfr[ni] = *(const bf16x8*)(Bs + row * 64 + pc * 8);
            }
            for (int mi = 0; mi < 4; ++mi)
                for (int ni = 0; ni < 2; ++ni)
                    acc[mi][ni] = __builtin_amdgcn_mfma_f32_16x16x32_bf16(
                        afr[mi], bfr[ni], acc[mi][ni], 0, 0, 0);
        }
        __syncthreads();
    }

    for (int ni = 0; ni < 2; ++ni) {
        int n    = n0 + wn + ni * 16 + mrow;
        float bv = f ? ((const float*)bias)[n] : (float)((const bf16*)bias)[n];
        for (int mi = 0; mi < 4; ++mi) {
            int mb = m0 + wm + mi * 16 + quad * 4;
            for (int r = 0; r < 4; ++r) {
                float val = acc[mi][ni][r] + bv;
                if (f) ((float*)Cout)[(size_t)(mb + r) * N + n] = val;
                else   ((bf16*)Cout)[(size_t)(mb + r) * N + n] = (bf16)val;
            }
        }
    }
}

// ---------------------------------------------------------------------------
// Flash attention v13 = exact v10 (proven 65.4us): 512 thr, 8 waves x 16
// q-rows, reg-P permlane transpose, XCD remap, 2-buffer __syncthreads loop,
// VALU row-sum + epilogue shuffle reduce.
// v12 post-mortem: MFMA row-sum regressed (65.4->74.7): absolute VALU time
// unchanged, +17% matrix-pipe time -> reverted.
// ---------------------------------------------------------------------------
__global__ __launch_bounds__(512, 4) void flash_attn(
    const bf16* __restrict__ Qp, const bf16* __restrict__ Kp,
    const bf16* __restrict__ Vt, const void* __restrict__ maskv,
    bf16* __restrict__ O, const int* __restrict__ flag) {
    __shared__ __attribute__((aligned(16))) bf16 Ks[2][4096];
    __shared__ __attribute__((aligned(16))) bf16 Vs[2][4096];

    const int f       = flag[0];
    const int useMask = flag[1];
    const int tid  = threadIdx.x;          // 0..511
    const int lane = tid & 63;
    const int w    = tid >> 6;             // 0..7
    const int quad = lane >> 4;
    const int c    = lane & 15;

    // XCD-aware remap: all 16 s0-blocks of one (b,h) land on one XCD.
    const int flat = blockIdx.x + 16 * (blockIdx.y + 16 * blockIdx.z);
    const int rx   = flat & 7;
    const int sx   = flat >> 3;
    const int pair = rx + 8 * (sx >> 4);
    const int s0   = (sx & 15) * 128;
    const int h    = pair & 15;
    const int b    = pair >> 4;

    const size_t qkBase = (size_t)b * 2048 * 1024 + h * 64;
    const size_t vtBase = ((size_t)b * 1024 + h * 64) * 2048;

    // staging: exactly one 16B K-chunk + one 16B V-chunk per thread
    const int r0 = tid >> 3, g0 = (tid & 7) ^ (r0 & 7);
    const bf16* kp0 = Kp + qkBase + (size_t)r0 * 1024 + g0 * 8;
    const bf16* vp0 = Vt + vtBase + (size_t)r0 * 2048 + g0 * 8;

#define STAGE(B_, T_) do {                                                      \
        async_load16(kp0 + (size_t)(T_) * 1024, &Ks[B_][(size_t)(w * 64) * 8]); \
        async_load16(vp0 + (T_),                &Vs[B_][(size_t)(w * 64) * 8]); \
    } while (0)

    // invariant per-lane LDS frag base pointers (q-independent)
    const bf16* kf0 = &Ks[0][c * 64 + ((0 + quad) ^ (c & 7)) * 8];
    const bf16* kf1 = &Ks[0][c * 64 + ((4 + quad) ^ (c & 7)) * 8];
    const bf16* vf0 = &Vs[0][c * 64 + ((0 + quad) ^ (c & 7)) * 8];
    const bf16* vf1 = &Vs[0][c * 64 + ((4 + quad) ^ (c & 7)) * 8];

    // Q fragment in registers: this wave's 16 rows as the MFMA B-operand
    const bf16* qrow = Qp + qkBase + (size_t)(s0 + w * 16 + c) * 1024;
    bf16x8 aq0 = *(const bf16x8*)(qrow + quad * 8);
    bf16x8 aq1 = *(const bf16x8*)(qrow + 32 + quad * 8);

    f32x4 o_acc[4] = {};   // [ni]: rows q = w*16+quad*4+r, col dv = ni*16+c
    float l_s = 0.f;

    const size_t mb0 = (size_t)(s0 + w * 16 + c) * 2048;

#define FCOMP(IB_, T_) do {                                                              \
        f32x4 sc[4] = {};                                                                \
        _Pragma("unroll") for (int tt = 0; tt < 4; ++tt) {                               \
            bf16x8 ak0 = *(const bf16x8*)(kf0 + (IB_) * 4096 + tt * 1024);               \
            bf16x8 ak1 = *(const bf16x8*)(kf1 + (IB_) * 4096 + tt * 1024);               \
            sc[tt] = __builtin_amdgcn_mfma_f32_16x16x32_bf16(ak0, aq0, sc[tt], 0, 0, 0); \
            sc[tt] = __builtin_amdgcn_mfma_f32_16x16x32_bf16(ak1, aq1, sc[tt], 0, 0, 0); \
        }                                                                                \
        if (useMask) {                                                                   \
            const size_t mr = mb0 + (T_);                                                \
            _Pragma("unroll") for (int tt = 0; tt < 4; ++tt) {                           \
                if (f) {                                                                 \
                    f32x4 mk = *(const f32x4*)((const float*)maskv + mr + tt * 16 + quad * 4); \
                    for (int r = 0; r < 4; ++r) sc[tt][r] += mk[r] * 1.44269504f;        \
                } else {                                                                 \
                    bf16x4 mk = *(const bf16x4*)((const bf16*)maskv + mr + tt * 16 + quad * 4); \
                    for (int r = 0; r < 4; ++r) sc[tt][r] += (float)mk[r] * 1.44269504f; \
                }                                                                        \
            }                                                                            \
        }                                                                                \
        unsigned Wp[4][2];                                                               \
        {                                                                                \
            float rsum = 0.f;                                                            \
            _Pragma("unroll") for (int tt = 0; tt < 4; ++tt) {                           \
                float p0 = exp2f(sc[tt][0]), p1 = exp2f(sc[tt][1]);                      \
                float p2 = exp2f(sc[tt][2]), p3 = exp2f(sc[tt][3]);                      \
                rsum += (p0 + p1) + (p2 + p3);                                           \
                Wp[tt][0] = pk2(p0, p1);                                                 \
                Wp[tt][1] = pk2(p2, p3);                                                 \
            }                                                                            \
            l_s += rsum;                                                                 \
        }                                                                                \
        _Pragma("unroll") for (int kk = 0; kk < 2; ++kk) {                               \
            unsigned a0 = Wp[2 * kk][0], b0v = Wp[2 * kk + 1][0];                        \
            unsigned a1 = Wp[2 * kk][1], b1v = Wp[2 * kk + 1][1];                        \
            PLSWAP32(a0, b0v);                                                           \
            PLSWAP16(a0, b0v);                                                           \
            PLSWAP32(a1, b1v);                                                           \
            PLSWAP16(a1, b1v);                                                           \
            u32x4 uv; uv[0] = a0; uv[1] = a1; uv[2] = b0v; uv[3] = b1v;                  \
            bf16x8 ap = __builtin_bit_cast(bf16x8, uv);                                  \
            const bf16* vfb = kk ? vf1 : vf0;                                            \
            _Pragma("unroll") for (int ni = 0; ni < 4; ++ni) {                           \
                bf16x8 bv = *(const bf16x8*)(vfb + (IB_) * 4096 + ni * 1024);            \
                o_acc[ni] = __builtin_amdgcn_mfma_f32_16x16x32_bf16(ap, bv, o_acc[ni], 0, 0, 0); \
            }                                                                            \
        }                                                                                \
    } while (0)

    STAGE(0, 0);
    for (int t0 = 0; t0 < 2048; t0 += 128) {
        __syncthreads();                       // buf0 staging visible
        STAGE(1, t0 + 64);
        FCOMP(0, t0);
        __syncthreads();                       // buf1 staging visible
        if (t0 + 128 < 2048) STAGE(0, t0 + 128);
        FCOMP(1, t0 + 64);
    }
#undef STAGE
#undef FCOMP

    // epilogue: reduce l across quads, gather per-row l, store O
    {
        float ls = l_s;
        ls += __shfl_xor(ls, 16, 64);
        ls += __shfl_xor(ls, 32, 64);
        for (int r = 0; r < 4; ++r) {
            float lv   = __shfl(ls, quad * 4 + r, 64);
            float inv  = 1.0f / lv;
            size_t roff = (size_t)(b * 2048 + s0 + w * 16 + quad * 4 + r) * 1024 + h * 64;
            for (int ni = 0; ni < 4; ++ni)
                O[roff + ni * 16 + c] = (bf16)(o_acc[ni][r] * inv);
        }
    }
}

// ---------------------------------------------------------------------------
extern "C" void kernel_launch(void* const* d_in, const int* in_sizes, int n_in,
                              void* d_out, int out_size, void* d_ws, size_t ws_size,
                              hipStream_t stream) {
    bf16* ws = (bf16*)d_ws;
    (void)in_sizes; (void)n_in; (void)out_size;

    const size_t MM = 1024 * 1024;
    int*  flag = (int*)ws;           // flag[0]=fp32?, flag[1]=mask-nonzero
    bf16* WqT  = ws + 8;             // 3 MM
    bf16* WoT  = WqT + 3 * MM;       // 1 MM
    bf16* Qp   = WoT + MM;           // 4 MM (pre-scaled by 0.125*log2e)
    bf16* Kp   = Qp + 4 * MM;        // 4 MM
    bf16* Xq   = Kp + 4 * MM;        // 4 MM (query bf16; becomes AO after flash)
    bf16* AO   = Xq;                 //        -> 16 MM + 8 (proven fit)
    bf16* Xk   = Xq + 4 * MM;        // 4 MM key bf16 (only if ws_size allows)
    bf16* Xv   = (bf16*)d_out;            // d_out lower 8 MB: value bf16
    bf16* Vt   = (bf16*)d_out + 4 * MM;   // d_out upper 8 MB: V^T (dead after flash)

    // Host guard: Xk needs ws up to 20 MM bf16 + 16 B of flags.
    const int useXk = (ws_size >= (size_t)(20 * MM) * sizeof(bf16) + 16) ? 1 : 0;

    detect_dtype<<<1, 256, 0, stream>>>((const unsigned short*)d_in[0], flag);

    prep<<<dim3(64, 32, useXk ? 8 : 7), 256, 0, stream>>>(
        d_in[0], d_in[2], d_in[1], d_in[4], d_in[6], d_in[8], d_in[10],
        (const unsigned int*)d_in[3], Xq, Xv, Xk, WqT, WoT, flag);

    gemm_qkv<<<dim3(8, 32, 3), 256, 0, stream>>>(Xq, d_in[1], Xv, Xk, WqT,
                                                 d_in[5], d_in[7], d_in[9],
                                                 Qp, Kp, Vt, flag, useXk);

    flash_attn<<<dim3(16, 16, 2), 512, 0, stream>>>(Qp, Kp, Vt, d_in[3], AO, flag);

    gemm_out<<<dim3(16, 32, 1), 256, 0, stream>>>(AO, WoT, d_in[11], d_out, flag);
}